// Round 23
// baseline (18.278 us; speedup 1.0000x reference)
//
#include <hip/hip_runtime.h>
#include <hip/hip_bf16.h>

#define NA 3
#define NT 32
#define NC 4
#define NR 8
#define NK 1024
#define NPIX 4096            // 64*64
#define NOUT (NT * NC * NK)  // 131072 complex outputs
#define NRK (NR * NK)        // 8192 (r,k) pairs
#define SP_LDS_BYTES 98304   // [12][4096] bf16, XOR-swizzled rows

typedef __attribute__((ext_vector_type(8))) short bf16x8;
typedef __attribute__((ext_vector_type(4))) short bf16x4;
typedef __attribute__((ext_vector_type(4))) float f32x4;

static __device__ __forceinline__ short f2bf(float f) {
    union { __hip_bfloat16 h; short s; } u;
    u.h = __float2bfloat16(f);
    return u.s;
}

// ---------------------------------------------------------------------------
// nudft_mono16b: r22's single-dispatch pipeline with (a) minimal-traffic
// pack (7 float4 loads/thread: each x/mps value read ONCE per block) and
// (b) phasor setup hoisted BEFORE the pack barrier (overlaps pack latency).
//  phase 0: inline detect (proven r13-r22): any |candA| > pi => candA is mps.
//  phase 1: pack: thread owns 4 pixels x all 12 channels ->
//           lds[ch][n] = bf16(x[a,n]*mps[c,n]), byte ^= ((row&7)<<4)
//           (8B chunks stay inside one 16B swizzle unit: rows are 64 px,
//            so the involution matches the b128 read side exactly; G21).
//  phase 1.5 (pre-barrier): trj loads + in-register Ex/Ey phasor chains
//           (r12-r22-proven, bitwise identical).
//  phase 2: wave w -> (chgrp = w&3 -> 3 ch, iq = w>>2 -> one 16-row slice);
//           2 rk-groups per A-load; 2 MFMAs (K=64) per (rkg, ch); f32
//           Ey-fold.  Lane rule: A/B j-slots = g*8+e+32h (r11-proven);
//           C row = g*4+reg (m89).  Partials -> ylds[4][12][32].
//  phase 3: fused combine epilogue; planar f32 out (r7-r22-proven).
// ---------------------------------------------------------------------------
__global__ __launch_bounds__(1024) void nudft_mono16b(
    const float* __restrict__ x,
    const float* __restrict__ candA,
    const float* __restrict__ candB,
    const float* __restrict__ phi,
    const float* __restrict__ dcf,
    const int*  __restrict__ sidx,
    float* __restrict__ out)
{
    extern __shared__ char lds[];            // SP_LDS_BYTES swizzled s'
    __shared__ int sfl;
    __shared__ float2 ylds[4][12][32];       // [iq][ch][k-local] 12 KB

    const int tid = threadIdx.x;

    // ---- phase 0: detect ----
    if (tid == 0) sfl = 0;
    __syncthreads();
    {
        const float4* A4 = (const float4*)candA;
        int loc = 0;
#pragma unroll
        for (int q = 0; q < 4; ++q) {
            const float4 v = A4[tid + q * 1024];
            if (fabsf(v.x) > 3.1416f || fabsf(v.y) > 3.1416f ||
                fabsf(v.z) > 3.1416f || fabsf(v.w) > 3.1416f) loc = 1;
        }
        if (loc) atomicOr(&sfl, 1);
    }
    __syncthreads();
    const int fl = sfl;
    const float* __restrict__ trj = fl ? candB : candA;
    const float* __restrict__ mps = fl ? candA : candB;

    // ---- phase 1: minimal-traffic pack (4 px/thread, all 12 channels) ----
    {
        const int p4 = tid * 4;                      // pixel base
        const int row = p4 >> 6;
        const int sw = (row & 7) << 4;
        float4 xv[3], mv[4];
#pragma unroll
        for (int a = 0; a < 3; ++a) xv[a] = *(const float4*)&x[a * NPIX + p4];
#pragma unroll
        for (int c = 0; c < 4; ++c) mv[c] = *(const float4*)&mps[c * NPIX + p4];
#pragma unroll
        for (int a = 0; a < 3; ++a) {
#pragma unroll
            for (int c = 0; c < 4; ++c) {
                const int ch = a * 4 + c;
                bf16x4 pk;
                pk[0] = f2bf(xv[a].x * mv[c].x);
                pk[1] = f2bf(xv[a].y * mv[c].y);
                pk[2] = f2bf(xv[a].z * mv[c].z);
                pk[3] = f2bf(xv[a].w * mv[c].w);
                *(bf16x4*)(lds + ((ch * 8192 + p4 * 2) ^ sw)) = pk;
            }
        }
    }

    // ---- phase 1.5 (PRE-barrier): trj loads + phasor chains ----
    const int w = tid >> 6, l = tid & 63, col = l & 15, g = l >> 4;
    const int chgrp = w & 3, iq = w >> 2;            // iq in 0..3
    const int rk0 = blockIdx.x * 32;
    const int r = rk0 >> 10, k0 = rk0 & (NK - 1);
    const int i0 = iq * 16;

    float t0a[2], t1a[2];
#pragma unroll
    for (int q = 0; q < 2; ++q) {
        const int k = k0 + q * 16 + col;
        t0a[q] = trj[(r * 2 + 0) * NK + k];
        t1a[q] = trj[(r * 2 + 1) * NK + k];
    }

    bf16x8 bre[2][2], bim[2][2];
#pragma unroll
    for (int q = 0; q < 2; ++q) {
        float pr[8], pi[8];
        float sr, cr; __sincosf(t1a[q], &sr, &cr);
        float s0, c0; __sincosf(t1a[q] * (float)(g * 8 - 32), &s0, &c0);
        pr[0] = c0; pi[0] = -s0;
#pragma unroll
        for (int e = 1; e < 8; ++e) {
            const float nr = pr[e-1] * cr + pi[e-1] * sr;
            const float ni = pi[e-1] * cr - pr[e-1] * sr;
            pr[e] = nr; pi[e] = ni;
        }
        union { bf16x8 v; short s[8]; } u0, u1;
#pragma unroll
        for (int e = 0; e < 8; ++e) { u0.s[e] = f2bf(pr[e]); u1.s[e] = f2bf(pi[e]); }
        bre[q][0] = u0.v; bim[q][0] = u1.v;
        float s32, c32; __sincosf(32.f * t1a[q], &s32, &c32);
#pragma unroll
        for (int e = 0; e < 8; ++e) {
            const float nr = pr[e] * c32 + pi[e] * s32;
            const float ni = pi[e] * c32 - pr[e] * s32;
            u0.s[e] = f2bf(nr); u1.s[e] = f2bf(ni);
        }
        bre[q][1] = u0.v; bim[q][1] = u1.v;
    }

    float eyR[2][4], eyI[2][4];
#pragma unroll
    for (int q = 0; q < 2; ++q) {
        float syr, cyr; __sincosf(t0a[q], &syr, &cyr);
        float sb, cb; __sincosf(t0a[q] * (float)(i0 + g * 4 - 32), &sb, &cb);
        eyR[q][0] = cb; eyI[q][0] = -sb;
#pragma unroll
        for (int j = 1; j < 4; ++j) {
            const float nr = eyR[q][j-1] * cyr + eyI[q][j-1] * syr;
            const float ni = eyI[q][j-1] * cyr - eyR[q][j-1] * syr;
            eyR[q][j] = nr; eyI[q][j] = ni;
        }
    }
    __syncthreads();

    // ---- phase 2: main (A-fragments from swizzled LDS) ----
    float yre[2][3] = {{0.f,0.f,0.f},{0.f,0.f,0.f}};
    float yim[2][3] = {{0.f,0.f,0.f},{0.f,0.f,0.f}};

#pragma unroll
    for (int cc = 0; cc < 3; ++cc) {
        const int ch = chgrp * 3 + cc;
        const int lin = ch * 8192 + (i0 + col) * 128 + g * 16;
        const int sw  = (col & 7) << 4;              // ((i0+col)&7)<<4, i0%16==0
        const bf16x8 a0 = *(const bf16x8*)(lds + (lin ^ sw));
        const bf16x8 a1 = *(const bf16x8*)(lds + ((lin + 64) ^ sw));
#pragma unroll
        for (int q = 0; q < 2; ++q) {
            f32x4 gre = {0.f, 0.f, 0.f, 0.f}, gim = {0.f, 0.f, 0.f, 0.f};
            gre = __builtin_amdgcn_mfma_f32_16x16x32_bf16(a0, bre[q][0], gre, 0, 0, 0);
            gre = __builtin_amdgcn_mfma_f32_16x16x32_bf16(a1, bre[q][1], gre, 0, 0, 0);
            gim = __builtin_amdgcn_mfma_f32_16x16x32_bf16(a0, bim[q][0], gim, 0, 0, 0);
            gim = __builtin_amdgcn_mfma_f32_16x16x32_bf16(a1, bim[q][1], gim, 0, 0, 0);
#pragma unroll
            for (int reg = 0; reg < 4; ++reg) {
                yre[q][cc] = fmaf(eyR[q][reg], gre[reg],
                              fmaf(-eyI[q][reg], gim[reg], yre[q][cc]));
                yim[q][cc] = fmaf(eyR[q][reg], gim[reg],
                              fmaf( eyI[q][reg], gre[reg], yim[q][cc]));
            }
        }
    }

    // reduce over g (lane bits 4,5), park partials in LDS
#pragma unroll
    for (int q = 0; q < 2; ++q) {
#pragma unroll
        for (int cc = 0; cc < 3; ++cc) {
            float vr = yre[q][cc], vi = yim[q][cc];
            vr += __shfl_xor(vr, 16); vi += __shfl_xor(vi, 16);
            vr += __shfl_xor(vr, 32); vi += __shfl_xor(vi, 32);
            if (g == 0)
                ylds[iq][chgrp * 3 + cc][q * 16 + col] = make_float2(vr, vi);
        }
    }
    __syncthreads();

    // ---- phase 3: fused combine epilogue (planar f32 out, proven) ----
    bool is64 = true;
#pragma unroll
    for (int i = 1; i < 32; i += 2) is64 = is64 && (sidx[i] == 0);
#pragma unroll
    for (int q = 0; q < 4; ++q) {
        const int item = tid + q * 1024;         // 32t x 4c x 32k = 4096
        const int kl = item & 31;
        const int c  = (item >> 5) & 3;
        const int t  = item >> 7;
        const int rt = is64 ? sidx[2 * t] : sidx[t];
        if (rt == r) {
            const float d = dcf[r * NK + k0 + kl];
            float ore = 0.f, oim = 0.f;
#pragma unroll
            for (int a = 0; a < NA; ++a) {
                const float p = phi[a * NT + t];
                const float2 v0 = ylds[0][a * 4 + c][kl];
                const float2 v1 = ylds[1][a * 4 + c][kl];
                const float2 v2 = ylds[2][a * 4 + c][kl];
                const float2 v3 = ylds[3][a * 4 + c][kl];
                ore = fmaf(p, (v0.x + v1.x) + (v2.x + v3.x), ore);
                oim = fmaf(p, (v0.y + v1.y) + (v2.y + v3.y), oim);
            }
            const int gid = t * 4096 + c * 1024 + k0 + kl;
            out[gid]        = ore * d;
            out[NOUT + gid] = oim * d;
        }
    }
}

// ---------------------------------------------------------------------------
extern "C" void kernel_launch(void* const* d_in, const int* in_sizes, int n_in,
                              void* d_out, int out_size, void* d_ws, size_t ws_size,
                              hipStream_t stream) {
    // size-signature input resolution (robust to permutation; doc order default)
    int ix = 0, i16a = 1, iphi = 2, i16b = 3, idcf = 4, isidx = 5;
    int f16[2]; int n16 = 0, fx = -1, fphi = -1, fdcf = -1, fsidx = -1;
    for (int i = 0; i < n_in; ++i) {
        const int s = in_sizes[i];
        if (s == 12288) fx = i;
        else if (s == 96) fphi = i;
        else if (s == 8192) fdcf = i;
        else if (s == 16384) { if (n16 < 2) f16[n16] = i; ++n16; }
        else if (s == 32 || s == 64) fsidx = i;
    }
    if (fx >= 0 && fphi >= 0 && fdcf >= 0 && fsidx >= 0 && n16 == 2) {
        ix = fx; iphi = fphi; idcf = fdcf; isidx = fsidx;
        i16a = f16[0]; i16b = f16[1];
    }

    static bool attr_set = false;
    if (!attr_set) {
        hipFuncSetAttribute((const void*)nudft_mono16b,
                            hipFuncAttributeMaxDynamicSharedMemorySize,
                            SP_LDS_BYTES);
        attr_set = true;
    }

    nudft_mono16b<<<NRK / 32, 1024, SP_LDS_BYTES, stream>>>(
        (const float*)d_in[ix], (const float*)d_in[i16a], (const float*)d_in[i16b],
        (const float*)d_in[iphi], (const float*)d_in[idcf], (const int*)d_in[isidx],
        (float*)d_out);
}

// Round 24
// 16.174 us; speedup vs baseline: 1.1301x; 1.1301x over previous
//
#include <hip/hip_runtime.h>
#include <hip/hip_bf16.h>

#define NA 3
#define NT 32
#define NC 4
#define NR 8
#define NK 1024
#define NPIX 4096            // 64*64
#define NOUT (NT * NC * NK)  // 131072 complex outputs
#define NRK (NR * NK)        // 8192 (r,k) pairs
#define SP_LDS_BYTES 98304   // [12][4096] bf16, XOR-swizzled rows

typedef __attribute__((ext_vector_type(8))) short bf16x8;
typedef __attribute__((ext_vector_type(4))) float f32x4;

static __device__ __forceinline__ short f2bf(float f) {
    union { __hip_bfloat16 h; short s; } u;
    u.h = __float2bfloat16(f);
    return u.s;
}

// ---------------------------------------------------------------------------
// nudft_mono16: single-dispatch pipeline, 16 waves/block (1024 thr).
// EXACT revert to round-22's measured-best kernel (16.15 us).
//  phase 0: inline detect (proven r13-r22): any |candA| > pi => candA is mps.
//  phase 1: cooperative pack of full s' into swizzled dynamic LDS
//           (lds[ch][n] = bf16(x*mps), byte ^= ((row&7)<<4)).
//  phase 2: wave w -> (chgrp = w&3 -> 3 channels, iq = w>>2 -> ONE 16-row
//           i-slice).  2 rk-groups per A-load (r20); in-register Ex/Ey
//           phasors (r12-r21-proven chains); 2 MFMAs (K=64) per (rkg,ch);
//           f32 Ey-fold.  Lane rule: A/B j-slots = g*8+e+32h (r11-proven);
//           C row = g*4+reg (m89).  Partials -> ylds[4][12][32].
//  phase 3: fused combine epilogue sums 4 partials; planar f32 out
//           (r7-r22-proven layout).
// ---------------------------------------------------------------------------
__global__ __launch_bounds__(1024) void nudft_mono16(
    const float* __restrict__ x,
    const float* __restrict__ candA,
    const float* __restrict__ candB,
    const float* __restrict__ phi,
    const float* __restrict__ dcf,
    const int*  __restrict__ sidx,
    float* __restrict__ out)
{
    extern __shared__ char lds[];            // SP_LDS_BYTES swizzled s'
    __shared__ int sfl;
    __shared__ float2 ylds[4][12][32];       // [iq][ch][k-local] 12 KB

    const int tid = threadIdx.x;

    // ---- phase 0: detect ----
    if (tid == 0) sfl = 0;
    __syncthreads();
    {
        const float4* A4 = (const float4*)candA;
        int loc = 0;
#pragma unroll
        for (int q = 0; q < 4; ++q) {
            const float4 v = A4[tid + q * 1024];
            if (fabsf(v.x) > 3.1416f || fabsf(v.y) > 3.1416f ||
                fabsf(v.z) > 3.1416f || fabsf(v.w) > 3.1416f) loc = 1;
        }
        if (loc) atomicOr(&sfl, 1);
    }
    __syncthreads();
    const int fl = sfl;
    const float* __restrict__ trj = fl ? candB : candA;
    const float* __restrict__ mps = fl ? candA : candB;

    // ---- phase 1: cooperative pack into swizzled LDS ----
#pragma unroll
    for (int jj = 0; jj < 6; ++jj) {
        const int job = tid + jj * 1024;             // 0..6143
        const int ch = job >> 9, p8 = (job & 511) * 8;
        const int a = ch >> 2, c = ch & 3;
        const float4 xv0 = *(const float4*)&x[a * NPIX + p8];
        const float4 xv1 = *(const float4*)&x[a * NPIX + p8 + 4];
        const float4 mv0 = *(const float4*)&mps[c * NPIX + p8];
        const float4 mv1 = *(const float4*)&mps[c * NPIX + p8 + 4];
        union { bf16x8 v; short s[8]; } pk;
        pk.s[0] = f2bf(xv0.x * mv0.x); pk.s[1] = f2bf(xv0.y * mv0.y);
        pk.s[2] = f2bf(xv0.z * mv0.z); pk.s[3] = f2bf(xv0.w * mv0.w);
        pk.s[4] = f2bf(xv1.x * mv1.x); pk.s[5] = f2bf(xv1.y * mv1.y);
        pk.s[6] = f2bf(xv1.z * mv1.z); pk.s[7] = f2bf(xv1.w * mv1.w);
        const int row = p8 >> 6;                     // image row (j-run)
        const int byteoff = (ch * 8192 + p8 * 2) ^ ((row & 7) << 4);
        *(bf16x8*)(lds + byteoff) = pk.v;
    }
    __syncthreads();

    // ---- phase 2: main ----
    const int w = tid >> 6, l = tid & 63, col = l & 15, g = l >> 4;
    const int chgrp = w & 3, iq = w >> 2;            // iq in 0..3
    const int rk0 = blockIdx.x * 32;
    const int r = rk0 >> 10, k0 = rk0 & (NK - 1);
    const int i0 = iq * 16;

    float t0a[2], t1a[2];
#pragma unroll
    for (int q = 0; q < 2; ++q) {
        const int k = k0 + q * 16 + col;
        t0a[q] = trj[(r * 2 + 0) * NK + k];
        t1a[q] = trj[(r * 2 + 1) * NK + k];
    }

    // Ex fragments for both rk-groups (r12-r21-proven chains)
    bf16x8 bre[2][2], bim[2][2];
#pragma unroll
    for (int q = 0; q < 2; ++q) {
        float pr[8], pi[8];
        float sr, cr; __sincosf(t1a[q], &sr, &cr);
        float s0, c0; __sincosf(t1a[q] * (float)(g * 8 - 32), &s0, &c0);
        pr[0] = c0; pi[0] = -s0;
#pragma unroll
        for (int e = 1; e < 8; ++e) {
            const float nr = pr[e-1] * cr + pi[e-1] * sr;
            const float ni = pi[e-1] * cr - pr[e-1] * sr;
            pr[e] = nr; pi[e] = ni;
        }
        union { bf16x8 v; short s[8]; } u0, u1;
#pragma unroll
        for (int e = 0; e < 8; ++e) { u0.s[e] = f2bf(pr[e]); u1.s[e] = f2bf(pi[e]); }
        bre[q][0] = u0.v; bim[q][0] = u1.v;
        float s32, c32; __sincosf(32.f * t1a[q], &s32, &c32);
#pragma unroll
        for (int e = 0; e < 8; ++e) {
            const float nr = pr[e] * c32 + pi[e] * s32;
            const float ni = pi[e] * c32 - pr[e] * s32;
            u0.s[e] = f2bf(nr); u1.s[e] = f2bf(ni);
        }
        bre[q][1] = u0.v; bim[q][1] = u1.v;
    }

    // Ey phasors: i = i0 + g*4 + reg (one slice per wave)
    float eyR[2][4], eyI[2][4];
#pragma unroll
    for (int q = 0; q < 2; ++q) {
        float syr, cyr; __sincosf(t0a[q], &syr, &cyr);
        float sb, cb; __sincosf(t0a[q] * (float)(i0 + g * 4 - 32), &sb, &cb);
        eyR[q][0] = cb; eyI[q][0] = -sb;
#pragma unroll
        for (int j = 1; j < 4; ++j) {
            const float nr = eyR[q][j-1] * cyr + eyI[q][j-1] * syr;
            const float ni = eyI[q][j-1] * cyr - eyR[q][j-1] * syr;
            eyR[q][j] = nr; eyI[q][j] = ni;
        }
    }

    float yre[2][3] = {{0.f,0.f,0.f},{0.f,0.f,0.f}};
    float yim[2][3] = {{0.f,0.f,0.f},{0.f,0.f,0.f}};

#pragma unroll
    for (int cc = 0; cc < 3; ++cc) {
        const int ch = chgrp * 3 + cc;
        // swizzled LDS read: linear byte = ch*8192 + (i0+col)*128 + g*16
        const int lin = ch * 8192 + (i0 + col) * 128 + g * 16;
        const int sw  = (col & 7) << 4;              // ((i0+col)&7)<<4, i0%16==0
        const bf16x8 a0 = *(const bf16x8*)(lds + (lin ^ sw));
        const bf16x8 a1 = *(const bf16x8*)(lds + ((lin + 64) ^ sw));
#pragma unroll
        for (int q = 0; q < 2; ++q) {
            f32x4 gre = {0.f, 0.f, 0.f, 0.f}, gim = {0.f, 0.f, 0.f, 0.f};
            gre = __builtin_amdgcn_mfma_f32_16x16x32_bf16(a0, bre[q][0], gre, 0, 0, 0);
            gre = __builtin_amdgcn_mfma_f32_16x16x32_bf16(a1, bre[q][1], gre, 0, 0, 0);
            gim = __builtin_amdgcn_mfma_f32_16x16x32_bf16(a0, bim[q][0], gim, 0, 0, 0);
            gim = __builtin_amdgcn_mfma_f32_16x16x32_bf16(a1, bim[q][1], gim, 0, 0, 0);
#pragma unroll
            for (int reg = 0; reg < 4; ++reg) {
                yre[q][cc] = fmaf(eyR[q][reg], gre[reg],
                              fmaf(-eyI[q][reg], gim[reg], yre[q][cc]));
                yim[q][cc] = fmaf(eyR[q][reg], gim[reg],
                              fmaf( eyI[q][reg], gre[reg], yim[q][cc]));
            }
        }
    }

    // reduce over g (lane bits 4,5), park partials in LDS
#pragma unroll
    for (int q = 0; q < 2; ++q) {
#pragma unroll
        for (int cc = 0; cc < 3; ++cc) {
            float vr = yre[q][cc], vi = yim[q][cc];
            vr += __shfl_xor(vr, 16); vi += __shfl_xor(vi, 16);
            vr += __shfl_xor(vr, 32); vi += __shfl_xor(vi, 32);
            if (g == 0)
                ylds[iq][chgrp * 3 + cc][q * 16 + col] = make_float2(vr, vi);
        }
    }
    __syncthreads();

    // ---- phase 3: fused combine epilogue (planar f32 out, proven) ----
    bool is64 = true;
#pragma unroll
    for (int i = 1; i < 32; i += 2) is64 = is64 && (sidx[i] == 0);
#pragma unroll
    for (int q = 0; q < 4; ++q) {
        const int item = tid + q * 1024;         // 32t x 4c x 32k = 4096
        const int kl = item & 31;
        const int c  = (item >> 5) & 3;
        const int t  = item >> 7;
        const int rt = is64 ? sidx[2 * t] : sidx[t];
        if (rt == r) {
            const float d = dcf[r * NK + k0 + kl];
            float ore = 0.f, oim = 0.f;
#pragma unroll
            for (int a = 0; a < NA; ++a) {
                const float p = phi[a * NT + t];
                const float2 v0 = ylds[0][a * 4 + c][kl];
                const float2 v1 = ylds[1][a * 4 + c][kl];
                const float2 v2 = ylds[2][a * 4 + c][kl];
                const float2 v3 = ylds[3][a * 4 + c][kl];
                ore = fmaf(p, (v0.x + v1.x) + (v2.x + v3.x), ore);
                oim = fmaf(p, (v0.y + v1.y) + (v2.y + v3.y), oim);
            }
            const int gid = t * 4096 + c * 1024 + k0 + kl;
            out[gid]        = ore * d;
            out[NOUT + gid] = oim * d;
        }
    }
}

// ---------------------------------------------------------------------------
extern "C" void kernel_launch(void* const* d_in, const int* in_sizes, int n_in,
                              void* d_out, int out_size, void* d_ws, size_t ws_size,
                              hipStream_t stream) {
    // size-signature input resolution (robust to permutation; doc order default)
    int ix = 0, i16a = 1, iphi = 2, i16b = 3, idcf = 4, isidx = 5;
    int f16[2]; int n16 = 0, fx = -1, fphi = -1, fdcf = -1, fsidx = -1;
    for (int i = 0; i < n_in; ++i) {
        const int s = in_sizes[i];
        if (s == 12288) fx = i;
        else if (s == 96) fphi = i;
        else if (s == 8192) fdcf = i;
        else if (s == 16384) { if (n16 < 2) f16[n16] = i; ++n16; }
        else if (s == 32 || s == 64) fsidx = i;
    }
    if (fx >= 0 && fphi >= 0 && fdcf >= 0 && fsidx >= 0 && n16 == 2) {
        ix = fx; iphi = fphi; idcf = fdcf; isidx = fsidx;
        i16a = f16[0]; i16b = f16[1];
    }

    static bool attr_set = false;
    if (!attr_set) {
        hipFuncSetAttribute((const void*)nudft_mono16,
                            hipFuncAttributeMaxDynamicSharedMemorySize,
                            SP_LDS_BYTES);
        attr_set = true;
    }

    nudft_mono16<<<NRK / 32, 1024, SP_LDS_BYTES, stream>>>(
        (const float*)d_in[ix], (const float*)d_in[i16a], (const float*)d_in[i16b],
        (const float*)d_in[iphi], (const float*)d_in[idcf], (const int*)d_in[isidx],
        (float*)d_out);
}